// Round 2
// baseline (7939.653 us; speedup 1.0000x reference)
//
#include <hip/hip_runtime.h>
#include <math.h>

#define N_PTS 16384
#define N_CLUSTERS 4096
#define KNN_K 16
#define C_IN 64
#define C_OUT 128
#define FAN_IN 67
#define N_ROWS (N_CLUSTERS * KNN_K)   // 65536

typedef float vf2 __attribute__((ext_vector_type(2)));

// ---------------------------------------------------------------------------
// init: pp[i] = |pos_i|^2 (reference op order, no FMA), zero colsum/colsumsq
// ---------------------------------------------------------------------------
__global__ void init_kernel(const float* __restrict__ pos, float* __restrict__ pp,
                            float* __restrict__ cz) {
#pragma clang fp contract(off)
    int i = blockIdx.x * 256 + threadIdx.x;
    if (i < N_PTS) {
        float a = pos[i * 3 + 0], b = pos[i * 3 + 1], c = pos[i * 3 + 2];
        pp[i] = ((a * a) + (b * b)) + (c * c);
    }
    if (blockIdx.x == 0 && threadIdx.x < 256) cz[threadIdx.x] = 0.0f;
}

// ---------------------------------------------------------------------------
// FPS v5: single block, 1024 threads, 16 points/thread in registers as
// float2 pairs (packed fp32 VALU).  vs v4 the per-step serial tail is cut:
//   - NO global memory ops in the loop: winner coords travel through LDS
//     (keyed u64 atomicMin: idx<<32 | f32bits -> min global idx wins, and
//     its coord bits ride along), clusters accumulate in a 16KB LDS array
//     and are bulk-stored coalesced after the loop.  So no barrier in the
//     loop drains vmcnt, and the ~300cyc post-barrier scalar L2 coord load
//     is replaced by 3 broadcast ds_read_b64 (~30cyc).
//   - the 16-wave same-address LDS atomicMax is replaced by per-wave plain
//     writes s_wm[w] + a post-barrier 16-wide max tree in all threads
//     (barrier2 separates reads from next step's writes, no rotation).
//   - running block max via v_max3 chain (-8 instrs/wave/step).
// Bit-exact vs reference: d = ((dx*dx)+(dy*dy))+(dz*dz) per element, no FMA;
// fmax/max3/min only SELECT values (inputs are >= +0, no NaN, no -0), so the
// block max is a bit-exact copy of some thread's bv; tie-break = min global
// index among value-matching points (within a thread: first local match,
// indices ascending) == jnp.argmax first-occurrence semantics.
// ---------------------------------------------------------------------------
__global__ __launch_bounds__(1024)
__attribute__((amdgpu_waves_per_eu(4, 4)))
void fps_kernel(const float* __restrict__ pos, int* __restrict__ clusters) {
#pragma clang fp contract(off)
    __shared__ __align__(16) float s_wm[16];           // per-wave max (overwritten each step)
    __shared__ unsigned long long s_cx[2], s_cy[2], s_cz[2];  // keyed winner coords, 2-slot rotation
    __shared__ int s_cluster[N_CLUSTERS];              // 16KB result accumulator
    const int t = threadIdx.x;
    const int w = t >> 6, lane = t & 63;

    vf2 ax[8], ay[8], az[8], mdv[8];
#pragma unroll
    for (int a = 0; a < 8; ++a) {
        const int g0 = t + ((2 * a) << 10);
        const int g1 = g0 + 1024;
        ax[a] = (vf2){pos[g0 * 3 + 0], pos[g1 * 3 + 0]};
        ay[a] = (vf2){pos[g0 * 3 + 1], pos[g1 * 3 + 1]};
        az[a] = (vf2){pos[g0 * 3 + 2], pos[g1 * 3 + 2]};
        mdv[a] = (vf2){__builtin_inff(), __builtin_inff()};
    }
    if (t == 0) s_cluster[0] = 0;
    if (t < 2) { s_cx[t] = ~0ULL; s_cy[t] = ~0ULL; s_cz[t] = ~0ULL; }
    float lx = pos[0], ly = pos[1], lz = pos[2];
    __syncthreads();

// f32 wave-max DPP stage: masked/invalid lanes contribute old=0, which is the
// identity for nonnegative distances. Result (full wave max) lands in lane 63.
#define VMAX_STAGE(CTRL, RM)                                                      \
    do {                                                                          \
        int o_ = __builtin_amdgcn_update_dpp(0, __float_as_int(wm), (CTRL), (RM), \
                                             0xF, false);                         \
        wm = fmaxf(wm, __int_as_float(o_));                                       \
    } while (0)

    for (int step = 1; step < N_CLUSTERS; ++step) {
        const int slot = step & 1;
        const vf2 lxv = (vf2){lx, lx}, lyv = (vf2){ly, ly}, lzv = (vf2){lz, lz};
        // --- packed min-distance update (per-element op order identical to
        //     reference); running block max via v_max3 chain ---
        float bv = 0.0f;
#pragma unroll
        for (int a = 0; a < 8; ++a) {
            vf2 dx = ax[a] - lxv;
            vf2 dy = ay[a] - lyv;
            vf2 dz = az[a] - lzv;
            vf2 d = ((dx * dx) + (dy * dy)) + (dz * dz);
            vf2 m = __builtin_elementwise_min(mdv[a], d);
            mdv[a] = m;
            bv = fmaxf(fmaxf(bv, m.x), m.y);   // v_max3
        }

        // --- wave64 f32 DPP max; result lands in lane 63; publish per-wave ---
        float wm = bv;
        VMAX_STAGE(0x111, 0xF);  // row_shr:1
        VMAX_STAGE(0x112, 0xF);  // row_shr:2
        VMAX_STAGE(0x114, 0xF);  // row_shr:4
        VMAX_STAGE(0x118, 0xF);  // row_shr:8
        VMAX_STAGE(0x142, 0xA);  // row_bcast:15 -> rows 1,3
        VMAX_STAGE(0x143, 0xC);  // row_bcast:31 -> rows 2,3
        if (lane == 63) s_wm[w] = wm;
        __syncthreads();  // barrier1: all wave maxima visible

        // --- all threads: block max from 16 per-wave values (broadcast reads) ---
        const float4 q0 = ((const float4*)s_wm)[0];
        const float4 q1 = ((const float4*)s_wm)[1];
        const float4 q2 = ((const float4*)s_wm)[2];
        const float4 q3 = ((const float4*)s_wm)[3];
        float b0 = fmaxf(fmaxf(q0.x, q0.y), fmaxf(q0.z, q0.w));
        float b1 = fmaxf(fmaxf(q1.x, q1.y), fmaxf(q1.z, q1.w));
        float b2 = fmaxf(fmaxf(q2.x, q2.y), fmaxf(q2.z, q2.w));
        float b3 = fmaxf(fmaxf(q3.x, q3.y), fmaxf(q3.z, q3.w));
        const float bmax = fmaxf(fmaxf(b0, b1), fmaxf(b2, b3));

        // reset the OTHER slot for step+1 (readers of it finished before
        // barrier1 of this step; writers of it start after barrier1 of step+1)
        if (t == 0) s_cx[slot ^ 1] = ~0ULL;
        else if (t == 1) s_cy[slot ^ 1] = ~0ULL;
        else if (t == 2) s_cz[slot ^ 1] = ~0ULL;

        // --- rare path: only value-matching threads (typically 1 of 1024)
        //     recover their first-matching local index AND its coords ---
        if (bv == bmax) {
            int bj = 0;
            float wx = 0.0f, wy = 0.0f, wz = 0.0f;
#pragma unroll
            for (int a = 7; a >= 0; --a) {
                const bool my = (mdv[a].y == bv);
                bj = my ? 2 * a + 1 : bj;
                wx = my ? ax[a].y : wx;
                wy = my ? ay[a].y : wy;
                wz = my ? az[a].y : wz;
                const bool mx = (mdv[a].x == bv);
                bj = mx ? 2 * a : bj;
                wx = mx ? ax[a].x : wx;
                wy = mx ? ay[a].x : wy;
                wz = mx ? az[a].x : wz;
            }
            const unsigned long long hi =
                ((unsigned long long)(unsigned int)(t + (bj << 10))) << 32;
            atomicMin(&s_cx[slot], hi | (unsigned long long)__float_as_uint(wx));
            atomicMin(&s_cy[slot], hi | (unsigned long long)__float_as_uint(wy));
            atomicMin(&s_cz[slot], hi | (unsigned long long)__float_as_uint(wz));
        }
        __syncthreads();  // barrier2: winner resolved

        const unsigned long long kx = s_cx[slot];
        const unsigned long long ky = s_cy[slot];
        const unsigned long long kz = s_cz[slot];
        lx = __uint_as_float((unsigned int)kx);
        ly = __uint_as_float((unsigned int)ky);
        lz = __uint_as_float((unsigned int)kz);
        if (t == 0) s_cluster[step] = (int)(kx >> 32);
    }
#undef VMAX_STAGE

    // bulk coalesced store of the cluster list
    __syncthreads();
    for (int i = t; i < N_CLUSTERS; i += 1024) clusters[i] = s_cluster[i];
}

// ---------------------------------------------------------------------------
// kNN: one block per cluster, 256 threads. d = (qq+pp) - 2*dot (dot FMA-
// ascending like BLAS), LDS distance array per 8192-chunk, 16 argmin rounds
// per chunk (tie -> lower index == stable top_k), exact merge of 2x16.
// Only the neighbor SET matters downstream.
// ---------------------------------------------------------------------------
__global__ __launch_bounds__(256) void knn_kernel(const float* __restrict__ pos,
                                                  const float* __restrict__ pp,
                                                  const int* __restrict__ clusters,
                                                  int* __restrict__ nbr) {
#pragma clang fp contract(off)
    __shared__ float s_d[8192];
    __shared__ float s_rv[4];
    __shared__ int   s_ri[4];
    __shared__ float s_tv[32];
    __shared__ int   s_ti[32];
    const int m = blockIdx.x, t = threadIdx.x;
    const int lane = t & 63, w = t >> 6;

    const int qi = clusters[m];
    const float qx = pos[qi * 3 + 0], qy = pos[qi * 3 + 1], qz = pos[qi * 3 + 2];
    const float qq = ((qx * qx) + (qy * qy)) + (qz * qz);

    for (int chunk = 0; chunk < 2; ++chunk) {
        const int base = chunk << 13;
        __syncthreads();  // protect s_d overwrite vs previous chunk's reads
        for (int i = t; i < 8192; i += 256) {
            const int p = base + i;
            float dot = fmaf(qx, pos[p * 3 + 0], 0.0f);
            dot = fmaf(qy, pos[p * 3 + 1], dot);
            dot = fmaf(qz, pos[p * 3 + 2], dot);
            s_d[i] = (qq + pp[p]) - 2.0f * dot;
        }
        __syncthreads();
        for (int r = 0; r < KNN_K; ++r) {
            float bv = __builtin_inff();
            int   bi = 0x7fffffff;
            for (int i = t; i < 8192; i += 256) {   // i ascending per thread
                float v = s_d[i];
                if (v < bv) { bv = v; bi = i; }     // strict < keeps first
            }
#pragma unroll
            for (int off = 32; off >= 1; off >>= 1) {
                float ov = __shfl_down(bv, off);
                int   oi = __shfl_down(bi, off);
                if (ov < bv || (ov == bv && oi < bi)) { bv = ov; bi = oi; }
            }
            if (lane == 0) { s_rv[w] = bv; s_ri[w] = bi; }
            __syncthreads();
            if (t == 0) {
                float fv = s_rv[0]; int fi = s_ri[0];
#pragma unroll
                for (int ww = 1; ww < 4; ++ww) {
                    if (s_rv[ww] < fv || (s_rv[ww] == fv && s_ri[ww] < fi)) {
                        fv = s_rv[ww]; fi = s_ri[ww];
                    }
                }
                s_tv[chunk * 16 + r] = fv;
                s_ti[chunk * 16 + r] = base + fi;
                s_d[fi] = __builtin_inff();
            }
            __syncthreads();
        }
    }
    if (t == 0) {   // exact merge of two sorted-by-(v,idx) lists
        int a = 0, b = 0;
        for (int r = 0; r < KNN_K; ++r) {
            bool takeA;
            if (b >= 16) takeA = true;
            else if (a >= 16) takeA = false;
            else {
                float va = s_tv[a], vb = s_tv[16 + b];
                takeA = (va < vb) || (va == vb && s_ti[a] < s_ti[16 + b]);
            }
            nbr[m * KNN_K + r] = takeA ? s_ti[a] : s_ti[16 + b];
            if (takeA) ++a; else ++b;
        }
    }
}

// ---------------------------------------------------------------------------
// MLP: grouped[r] = [pos[n]-pos[r>>4] (quirky full-pos indexing!), x[n]],
// h = grouped @ W^T.  PASS 1: accumulate column sum/sumsq.  PASS 2:
// recompute, y = scale*h+shift, out[m,c] = relu(max_k y) (relu∘max=max∘relu),
// plus sub_pos / sub_batch.  64 rows (= 4 whole clusters) x 128 cols / block.
// ---------------------------------------------------------------------------
template <int PASS>
__global__ __launch_bounds__(256) void mlp_kernel(const float* __restrict__ x,
                                                  const float* __restrict__ pos,
                                                  const int* __restrict__ nbr,
                                                  const float* __restrict__ W,
                                                  float* __restrict__ colsum,
                                                  float* __restrict__ colsumsq,
                                                  const float* __restrict__ ss,
                                                  const int* __restrict__ clusters,
                                                  const int* __restrict__ batch,
                                                  float* __restrict__ out) {
    __shared__ __align__(16) float At[FAN_IN][68];     // [i][r], pad 68
    __shared__ __align__(16) float Wl[FAN_IN * 132];   // [i][c], pad 132
    __shared__ float red0[128], red1[128];
    __shared__ float hm[8][132];                       // pass2 half-cluster maxima
    const int tid = threadIdx.x;
    const int R0 = blockIdx.x * 64;

    // stage W transposed
    for (int idx = tid; idx < FAN_IN * 128; idx += 256) {
        int i = idx >> 7, c = idx & 127;
        Wl[i * 132 + c] = W[c * FAN_IN + i];
    }
    // stage A transposed (gather)
    {
        const int wv = tid >> 6, lane = tid & 63;
        for (int r = wv; r < 64; r += 4) {
            const int R = R0 + r;
            const int n = nbr[R];
            At[3 + lane][r] = x[n * C_IN + lane];
            if (lane < 3) {
                const int q = R >> 4;  // faithful to source: cluster ORDINAL indexes pos
                At[lane][r] = pos[n * 3 + lane] - pos[q * 3 + lane];
            }
        }
    }
    if (PASS == 1 && tid < 128) { red0[tid] = 0.0f; red1[tid] = 0.0f; }
    __syncthreads();

    const int g = tid & 31, rg = tid >> 5;
    const int c0 = g * 4, r0 = rg * 8;
    float acc[8][4];
#pragma unroll
    for (int a = 0; a < 8; ++a)
#pragma unroll
        for (int b = 0; b < 4; ++b) acc[a][b] = 0.0f;

    for (int i = 0; i < FAN_IN; ++i) {
        const float4 w4 = *(const float4*)&Wl[i * 132 + c0];
        const float4 a0 = *(const float4*)&At[i][r0];
        const float4 a1 = *(const float4*)&At[i][r0 + 4];
        const float av[8] = {a0.x, a0.y, a0.z, a0.w, a1.x, a1.y, a1.z, a1.w};
        const float wv4[4] = {w4.x, w4.y, w4.z, w4.w};
#pragma unroll
        for (int a = 0; a < 8; ++a)
#pragma unroll
            for (int b = 0; b < 4; ++b) acc[a][b] = fmaf(av[a], wv4[b], acc[a][b]);
    }

    if (PASS == 1) {
#pragma unroll
        for (int b = 0; b < 4; ++b) {
            float s = 0.0f, sq = 0.0f;
#pragma unroll
            for (int a = 0; a < 8; ++a) {
                s += acc[a][b];
                sq = fmaf(acc[a][b], acc[a][b], sq);
            }
            atomicAdd(&red0[c0 + b], s);
            atomicAdd(&red1[c0 + b], sq);
        }
        __syncthreads();
        if (tid < 128) {
            atomicAdd(&colsum[tid], red0[tid]);
            atomicAdd(&colsumsq[tid], red1[tid]);
        }
    } else {
        // rows r0..r0+7 lie in ONE cluster (half of it): reduce then combine
#pragma unroll
        for (int b = 0; b < 4; ++b) {
            const float sc = ss[c0 + b], sh = ss[128 + c0 + b];
            float mx = -__builtin_inff();
#pragma unroll
            for (int a = 0; a < 8; ++a) mx = fmaxf(mx, fmaf(sc, acc[a][b], sh));
            hm[rg][c0 + b] = mx;
        }
        __syncthreads();
        for (int o = tid; o < 512; o += 256) {
            const int cl = o >> 7, c = o & 127;
            const float v = fmaxf(hm[2 * cl][c], hm[2 * cl + 1][c]);
            const int M = blockIdx.x * 4 + cl;
            out[M * 128 + c] = fmaxf(v, 0.0f);
        }
        if (tid < 12) {
            const int cl = tid / 3, l = tid % 3;
            const int M = blockIdx.x * 4 + cl;
            out[524288 + M * 3 + l] = pos[clusters[M] * 3 + l];
        } else if (tid < 16) {
            const int M = blockIdx.x * 4 + (tid - 12);
            out[536576 + M] = (float)batch[clusters[M]];
        }
    }
}

// ---------------------------------------------------------------------------
// stats: scale/shift from column sums (biased var, like torch BN training)
// ---------------------------------------------------------------------------
__global__ void stats_kernel(const float* __restrict__ colsum,
                             const float* __restrict__ colsumsq,
                             const float* __restrict__ gamma,
                             const float* __restrict__ beta,
                             float* __restrict__ ss) {
    const int c = threadIdx.x;
    const float inv_n = 1.0f / (float)N_ROWS;
    const float mean = colsum[c] * inv_n;
    float var = colsumsq[c] * inv_n - mean * mean;
    var = fmaxf(var, 0.0f);
    const float inv = rsqrtf(var + 1e-5f);
    const float sc = gamma[c] * inv;
    ss[c] = sc;
    ss[128 + c] = beta[c] - mean * sc;
}

// ---------------------------------------------------------------------------
extern "C" void kernel_launch(void* const* d_in, const int* in_sizes, int n_in,
                              void* d_out, int out_size, void* d_ws, size_t ws_size,
                              hipStream_t stream) {
    const float* x     = (const float*)d_in[0];
    const float* pos   = (const float*)d_in[1];
    const int*   batch = (const int*)d_in[2];
    const float* W     = (const float*)d_in[3];
    const float* gamma = (const float*)d_in[4];
    const float* beta  = (const float*)d_in[5];
    float* out = (float*)d_out;
    float* wsf = (float*)d_ws;

    int*   clusters = (int*)d_ws;            // [4096]
    int*   nbr      = clusters + 4096;       // [65536]
    float* pp       = wsf + 69632;           // [16384]
    float* colsum   = wsf + 86016;           // [128]
    float* colsumsq = wsf + 86144;           // [128]
    float* ss       = wsf + 86272;           // [256]

    init_kernel<<<dim3(64), dim3(256), 0, stream>>>(pos, pp, colsum);
    fps_kernel<<<dim3(1), dim3(1024), 0, stream>>>(pos, clusters);
    knn_kernel<<<dim3(N_CLUSTERS), dim3(256), 0, stream>>>(pos, pp, clusters, nbr);
    mlp_kernel<1><<<dim3(1024), dim3(256), 0, stream>>>(x, pos, nbr, W, colsum, colsumsq,
                                                        ss, clusters, batch, out);
    stats_kernel<<<dim3(1), dim3(128), 0, stream>>>(colsum, colsumsq, gamma, beta, ss);
    mlp_kernel<2><<<dim3(1024), dim3(256), 0, stream>>>(x, pos, nbr, W, colsum, colsumsq,
                                                        ss, clusters, batch, out);
}

// Round 3
// 6437.188 us; speedup vs baseline: 1.2334x; 1.2334x over previous
//
#include <hip/hip_runtime.h>
#include <math.h>

#define N_PTS 16384
#define N_CLUSTERS 4096
#define KNN_K 16
#define C_IN 64
#define C_OUT 128
#define FAN_IN 67
#define N_ROWS (N_CLUSTERS * KNN_K)   // 65536

typedef float vf2 __attribute__((ext_vector_type(2)));

// ---------------------------------------------------------------------------
// init: pp[i] = |pos_i|^2 (reference op order, no FMA), zero colsum/colsumsq
// ---------------------------------------------------------------------------
__global__ void init_kernel(const float* __restrict__ pos, float* __restrict__ pp,
                            float* __restrict__ cz) {
#pragma clang fp contract(off)
    int i = blockIdx.x * 256 + threadIdx.x;
    if (i < N_PTS) {
        float a = pos[i * 3 + 0], b = pos[i * 3 + 1], c = pos[i * 3 + 2];
        pp[i] = ((a * a) + (b * b)) + (c * c);
    }
    if (blockIdx.x == 0 && threadIdx.x < 256) cz[threadIdx.x] = 0.0f;
}

// ---------------------------------------------------------------------------
// FPS v6: single block, 512 threads (8 waves, 2/SIMD), 32 points/thread in
// registers as float2 pairs (packed fp32 VALU).
// Rationale (v5 post-mortem): the per-step VALU issue floor (~600cyc, 16K pts)
// is thread-count-invariant, but the serial tail (barrier arrival spread,
// same-address reduce chain, post-barrier issue) scales with WAVE COUNT, and
// per-thread LDS reads cost (reads/thread x waves) in pipe occupancy.  So:
//   - 512 threads instead of 1024: halves barrier spread + post-barrier issue.
//   - cross-wave value reduce: lane63 plain-writes s_wm[w] (8 floats), then
//     after barrier1 each thread reads 2x ds_read_b128 + 7 fmax tree.  At 8
//     waves this is only 16 LDS reads/step (~190 pipe cyc) -- v5's mistake
//     was this same pattern at 16 waves x 4 reads (~770 cyc).
//   - winner coords via readfirstlane + scalar load (v4-proven, scalar cache,
//     does not touch VALU/LDS pipes).
//   - cluster ids accumulate in LDS (single ds_write by t0), bulk-stored
//     after the loop: no global store -> no vmcnt drain at loop barriers.
// Bit-exact vs reference: d = ((dx*dx)+(dy*dy))+(dz*dz) per element, no FMA;
// fmax/min only SELECT values (inputs >= +0, no NaN/-0: squares), so bmax is
// a bit-exact copy of some thread's bv; tie-break = min global index among
// value-matching points (per-thread: first local match, indices ascending;
// across threads: atomicMin of global index) == jnp.argmax first-occurrence.
// ---------------------------------------------------------------------------
__global__ __launch_bounds__(512)
__attribute__((amdgpu_waves_per_eu(2, 2)))
void fps_kernel(const float* __restrict__ pos, int* __restrict__ clusters) {
#pragma clang fp contract(off)
    __shared__ __align__(16) float s_wm[8];   // per-wave max, plain writes
    __shared__ unsigned int s_idx[4];          // winner idx, 4-slot rotation
    __shared__ int s_cluster[N_CLUSTERS];      // 16KB result accumulator
    const int t = threadIdx.x;
    const int w = t >> 6, lane = t & 63;

    vf2 ax[16], ay[16], az[16], mdv[16];
#pragma unroll
    for (int a = 0; a < 16; ++a) {
        const int g0 = t + ((2 * a) << 9);
        const int g1 = g0 + 512;
        ax[a] = (vf2){pos[g0 * 3 + 0], pos[g1 * 3 + 0]};
        ay[a] = (vf2){pos[g0 * 3 + 1], pos[g1 * 3 + 1]};
        az[a] = (vf2){pos[g0 * 3 + 2], pos[g1 * 3 + 2]};
        mdv[a] = (vf2){__builtin_inff(), __builtin_inff()};
    }
    if (t == 0) s_cluster[0] = 0;
    if (t < 4) s_idx[t] = 0xffffffffu;
    float lx = pos[0], ly = pos[1], lz = pos[2];
    __syncthreads();

// f32 wave-max DPP stage: masked/invalid lanes contribute old=0, which is the
// identity for nonnegative distances. Result (full wave max) lands in lane 63.
#define VMAX_STAGE(CTRL, RM)                                                      \
    do {                                                                          \
        int o_ = __builtin_amdgcn_update_dpp(0, __float_as_int(wm), (CTRL), (RM), \
                                             0xF, false);                         \
        wm = fmaxf(wm, __int_as_float(o_));                                       \
    } while (0)

    for (int step = 1; step < N_CLUSTERS; ++step) {
        const vf2 lxv = (vf2){lx, lx}, lyv = (vf2){ly, ly}, lzv = (vf2){lz, lz};
        // --- packed min-distance update (per-element op order identical to
        //     reference), running packed max ---
        vf2 bm = (vf2){0.0f, 0.0f};
#pragma unroll
        for (int a = 0; a < 16; ++a) {
            vf2 dx = ax[a] - lxv;
            vf2 dy = ay[a] - lyv;
            vf2 dz = az[a] - lzv;
            vf2 d = ((dx * dx) + (dy * dy)) + (dz * dz);
            vf2 m = __builtin_elementwise_min(mdv[a], d);
            mdv[a] = m;
            bm = __builtin_elementwise_max(bm, m);
        }
        const float bv = fmaxf(bm.x, bm.y);

        // --- wave64 f32 DPP max; result lands in lane 63; publish per-wave ---
        float wm = bv;
        VMAX_STAGE(0x111, 0xF);  // row_shr:1
        VMAX_STAGE(0x112, 0xF);  // row_shr:2
        VMAX_STAGE(0x114, 0xF);  // row_shr:4
        VMAX_STAGE(0x118, 0xF);  // row_shr:8
        VMAX_STAGE(0x142, 0xA);  // row_bcast:15 -> rows 1,3
        VMAX_STAGE(0x143, 0xC);  // row_bcast:31 -> rows 2,3
        if (lane == 63) s_wm[w] = wm;
        // reset idx slot for step+2 (its last readers finished at step-2;
        // its next writers start after barrier1 of step+2)
        if (t == 0) s_idx[(step + 2) & 3] = 0xffffffffu;
        __syncthreads();  // barrier1: all 8 wave maxima visible

        // --- block max: 2x ds_read_b128 (broadcast) + 7-fmax tree ---
        const float4 q0 = ((const float4*)s_wm)[0];
        const float4 q1 = ((const float4*)s_wm)[1];
        const float bmax = fmaxf(fmaxf(fmaxf(q0.x, q0.y), fmaxf(q0.z, q0.w)),
                                 fmaxf(fmaxf(q1.x, q1.y), fmaxf(q1.z, q1.w)));

        // --- rare path: only value-matching threads (typically 1 of 512)
        //     recover their first-matching local index (static indexing) ---
        if (bv == bmax) {
            int bj = 0;
#pragma unroll
            for (int a = 15; a >= 0; --a) {
                bj = (mdv[a].y == bv) ? 2 * a + 1 : bj;
                bj = (mdv[a].x == bv) ? 2 * a : bj;
            }
            atomicMin(&s_idx[step & 3], (unsigned int)(t + (bj << 9)));
        }
        __syncthreads();  // barrier2: winner resolved

        const unsigned int win = s_idx[step & 3];
        if (t == 0) s_cluster[step] = (int)win;
        // uniform scalar fetch of winner coords (scalar cache; off VALU/LDS pipes)
        const unsigned int winu = (unsigned int)__builtin_amdgcn_readfirstlane((int)win);
        lx = pos[winu * 3 + 0];
        ly = pos[winu * 3 + 1];
        lz = pos[winu * 3 + 2];
    }
#undef VMAX_STAGE

    // bulk coalesced store of the cluster list
    __syncthreads();
    for (int i = t; i < N_CLUSTERS; i += 512) clusters[i] = s_cluster[i];
}

// ---------------------------------------------------------------------------
// kNN: one block per cluster, 256 threads. d = (qq+pp) - 2*dot (dot FMA-
// ascending like BLAS), LDS distance array per 8192-chunk, 16 argmin rounds
// per chunk (tie -> lower index == stable top_k), exact merge of 2x16.
// Only the neighbor SET matters downstream.
// ---------------------------------------------------------------------------
__global__ __launch_bounds__(256) void knn_kernel(const float* __restrict__ pos,
                                                  const float* __restrict__ pp,
                                                  const int* __restrict__ clusters,
                                                  int* __restrict__ nbr) {
#pragma clang fp contract(off)
    __shared__ float s_d[8192];
    __shared__ float s_rv[4];
    __shared__ int   s_ri[4];
    __shared__ float s_tv[32];
    __shared__ int   s_ti[32];
    const int m = blockIdx.x, t = threadIdx.x;
    const int lane = t & 63, w = t >> 6;

    const int qi = clusters[m];
    const float qx = pos[qi * 3 + 0], qy = pos[qi * 3 + 1], qz = pos[qi * 3 + 2];
    const float qq = ((qx * qx) + (qy * qy)) + (qz * qz);

    for (int chunk = 0; chunk < 2; ++chunk) {
        const int base = chunk << 13;
        __syncthreads();  // protect s_d overwrite vs previous chunk's reads
        for (int i = t; i < 8192; i += 256) {
            const int p = base + i;
            float dot = fmaf(qx, pos[p * 3 + 0], 0.0f);
            dot = fmaf(qy, pos[p * 3 + 1], dot);
            dot = fmaf(qz, pos[p * 3 + 2], dot);
            s_d[i] = (qq + pp[p]) - 2.0f * dot;
        }
        __syncthreads();
        for (int r = 0; r < KNN_K; ++r) {
            float bv = __builtin_inff();
            int   bi = 0x7fffffff;
            for (int i = t; i < 8192; i += 256) {   // i ascending per thread
                float v = s_d[i];
                if (v < bv) { bv = v; bi = i; }     // strict < keeps first
            }
#pragma unroll
            for (int off = 32; off >= 1; off >>= 1) {
                float ov = __shfl_down(bv, off);
                int   oi = __shfl_down(bi, off);
                if (ov < bv || (ov == bv && oi < bi)) { bv = ov; bi = oi; }
            }
            if (lane == 0) { s_rv[w] = bv; s_ri[w] = bi; }
            __syncthreads();
            if (t == 0) {
                float fv = s_rv[0]; int fi = s_ri[0];
#pragma unroll
                for (int ww = 1; ww < 4; ++ww) {
                    if (s_rv[ww] < fv || (s_rv[ww] == fv && s_ri[ww] < fi)) {
                        fv = s_rv[ww]; fi = s_ri[ww];
                    }
                }
                s_tv[chunk * 16 + r] = fv;
                s_ti[chunk * 16 + r] = base + fi;
                s_d[fi] = __builtin_inff();
            }
            __syncthreads();
        }
    }
    if (t == 0) {   // exact merge of two sorted-by-(v,idx) lists
        int a = 0, b = 0;
        for (int r = 0; r < KNN_K; ++r) {
            bool takeA;
            if (b >= 16) takeA = true;
            else if (a >= 16) takeA = false;
            else {
                float va = s_tv[a], vb = s_tv[16 + b];
                takeA = (va < vb) || (va == vb && s_ti[a] < s_ti[16 + b]);
            }
            nbr[m * KNN_K + r] = takeA ? s_ti[a] : s_ti[16 + b];
            if (takeA) ++a; else ++b;
        }
    }
}

// ---------------------------------------------------------------------------
// MLP: grouped[r] = [pos[n]-pos[r>>4] (quirky full-pos indexing!), x[n]],
// h = grouped @ W^T.  PASS 1: accumulate column sum/sumsq.  PASS 2:
// recompute, y = scale*h+shift, out[m,c] = relu(max_k y) (relu∘max=max∘relu),
// plus sub_pos / sub_batch.  64 rows (= 4 whole clusters) x 128 cols / block.
// ---------------------------------------------------------------------------
template <int PASS>
__global__ __launch_bounds__(256) void mlp_kernel(const float* __restrict__ x,
                                                  const float* __restrict__ pos,
                                                  const int* __restrict__ nbr,
                                                  const float* __restrict__ W,
                                                  float* __restrict__ colsum,
                                                  float* __restrict__ colsumsq,
                                                  const float* __restrict__ ss,
                                                  const int* __restrict__ clusters,
                                                  const int* __restrict__ batch,
                                                  float* __restrict__ out) {
    __shared__ __align__(16) float At[FAN_IN][68];     // [i][r], pad 68
    __shared__ __align__(16) float Wl[FAN_IN * 132];   // [i][c], pad 132
    __shared__ float red0[128], red1[128];
    __shared__ float hm[8][132];                       // pass2 half-cluster maxima
    const int tid = threadIdx.x;
    const int R0 = blockIdx.x * 64;

    // stage W transposed
    for (int idx = tid; idx < FAN_IN * 128; idx += 256) {
        int i = idx >> 7, c = idx & 127;
        Wl[i * 132 + c] = W[c * FAN_IN + i];
    }
    // stage A transposed (gather)
    {
        const int wv = tid >> 6, lane = tid & 63;
        for (int r = wv; r < 64; r += 4) {
            const int R = R0 + r;
            const int n = nbr[R];
            At[3 + lane][r] = x[n * C_IN + lane];
            if (lane < 3) {
                const int q = R >> 4;  // faithful to source: cluster ORDINAL indexes pos
                At[lane][r] = pos[n * 3 + lane] - pos[q * 3 + lane];
            }
        }
    }
    if (PASS == 1 && tid < 128) { red0[tid] = 0.0f; red1[tid] = 0.0f; }
    __syncthreads();

    const int g = tid & 31, rg = tid >> 5;
    const int c0 = g * 4, r0 = rg * 8;
    float acc[8][4];
#pragma unroll
    for (int a = 0; a < 8; ++a)
#pragma unroll
        for (int b = 0; b < 4; ++b) acc[a][b] = 0.0f;

    for (int i = 0; i < FAN_IN; ++i) {
        const float4 w4 = *(const float4*)&Wl[i * 132 + c0];
        const float4 a0 = *(const float4*)&At[i][r0];
        const float4 a1 = *(const float4*)&At[i][r0 + 4];
        const float av[8] = {a0.x, a0.y, a0.z, a0.w, a1.x, a1.y, a1.z, a1.w};
        const float wv4[4] = {w4.x, w4.y, w4.z, w4.w};
#pragma unroll
        for (int a = 0; a < 8; ++a)
#pragma unroll
            for (int b = 0; b < 4; ++b) acc[a][b] = fmaf(av[a], wv4[b], acc[a][b]);
    }

    if (PASS == 1) {
#pragma unroll
        for (int b = 0; b < 4; ++b) {
            float s = 0.0f, sq = 0.0f;
#pragma unroll
            for (int a = 0; a < 8; ++a) {
                s += acc[a][b];
                sq = fmaf(acc[a][b], acc[a][b], sq);
            }
            atomicAdd(&red0[c0 + b], s);
            atomicAdd(&red1[c0 + b], sq);
        }
        __syncthreads();
        if (tid < 128) {
            atomicAdd(&colsum[tid], red0[tid]);
            atomicAdd(&colsumsq[tid], red1[tid]);
        }
    } else {
        // rows r0..r0+7 lie in ONE cluster (half of it): reduce then combine
#pragma unroll
        for (int b = 0; b < 4; ++b) {
            const float sc = ss[c0 + b], sh = ss[128 + c0 + b];
            float mx = -__builtin_inff();
#pragma unroll
            for (int a = 0; a < 8; ++a) mx = fmaxf(mx, fmaf(sc, acc[a][b], sh));
            hm[rg][c0 + b] = mx;
        }
        __syncthreads();
        for (int o = tid; o < 512; o += 256) {
            const int cl = o >> 7, c = o & 127;
            const float v = fmaxf(hm[2 * cl][c], hm[2 * cl + 1][c]);
            const int M = blockIdx.x * 4 + cl;
            out[M * 128 + c] = fmaxf(v, 0.0f);
        }
        if (tid < 12) {
            const int cl = tid / 3, l = tid % 3;
            const int M = blockIdx.x * 4 + cl;
            out[524288 + M * 3 + l] = pos[clusters[M] * 3 + l];
        } else if (tid < 16) {
            const int M = blockIdx.x * 4 + (tid - 12);
            out[536576 + M] = (float)batch[clusters[M]];
        }
    }
}

// ---------------------------------------------------------------------------
// stats: scale/shift from column sums (biased var, like torch BN training)
// ---------------------------------------------------------------------------
__global__ void stats_kernel(const float* __restrict__ colsum,
                             const float* __restrict__ colsumsq,
                             const float* __restrict__ gamma,
                             const float* __restrict__ beta,
                             float* __restrict__ ss) {
    const int c = threadIdx.x;
    const float inv_n = 1.0f / (float)N_ROWS;
    const float mean = colsum[c] * inv_n;
    float var = colsumsq[c] * inv_n - mean * mean;
    var = fmaxf(var, 0.0f);
    const float inv = rsqrtf(var + 1e-5f);
    const float sc = gamma[c] * inv;
    ss[c] = sc;
    ss[128 + c] = beta[c] - mean * sc;
}

// ---------------------------------------------------------------------------
extern "C" void kernel_launch(void* const* d_in, const int* in_sizes, int n_in,
                              void* d_out, int out_size, void* d_ws, size_t ws_size,
                              hipStream_t stream) {
    const float* x     = (const float*)d_in[0];
    const float* pos   = (const float*)d_in[1];
    const int*   batch = (const int*)d_in[2];
    const float* W     = (const float*)d_in[3];
    const float* gamma = (const float*)d_in[4];
    const float* beta  = (const float*)d_in[5];
    float* out = (float*)d_out;
    float* wsf = (float*)d_ws;

    int*   clusters = (int*)d_ws;            // [4096]
    int*   nbr      = clusters + 4096;       // [65536]
    float* pp       = wsf + 69632;           // [16384]
    float* colsum   = wsf + 86016;           // [128]
    float* colsumsq = wsf + 86144;           // [128]
    float* ss       = wsf + 86272;           // [256]

    init_kernel<<<dim3(64), dim3(256), 0, stream>>>(pos, pp, colsum);
    fps_kernel<<<dim3(1), dim3(512), 0, stream>>>(pos, clusters);
    knn_kernel<<<dim3(N_CLUSTERS), dim3(256), 0, stream>>>(pos, pp, clusters, nbr);
    mlp_kernel<1><<<dim3(1024), dim3(256), 0, stream>>>(x, pos, nbr, W, colsum, colsumsq,
                                                        ss, clusters, batch, out);
    stats_kernel<<<dim3(1), dim3(128), 0, stream>>>(colsum, colsumsq, gamma, beta, ss);
    mlp_kernel<2><<<dim3(1024), dim3(256), 0, stream>>>(x, pos, nbr, W, colsum, colsumsq,
                                                        ss, clusters, batch, out);
}